// Round 3
// baseline (255.732 us; speedup 1.0000x reference)
//
#include <hip/hip_runtime.h>

#define BLOCK 256
#define CHUNK 4096                     // elements per block
#define NITER (CHUNK / (BLOCK * 4))    // 4 iterations of float4

typedef unsigned long long u64;

__device__ __forceinline__ float wave_incl_scan(float v, int lane) {
#pragma unroll
    for (int off = 1; off < 64; off <<= 1) {
        float u = __shfl_up(v, off);
        if (lane >= off) v += u;
    }
    return v;
}

__device__ __forceinline__ float wave_reduce(float v) {
#pragma unroll
    for (int off = 32; off >= 1; off >>= 1) v += __shfl_down(v, off);
    return v;  // valid in lane 0
}

__device__ __forceinline__ float wave_reduce_bcast(float v) {
    v = wave_reduce(v);
    return __shfl(v, 0);
}

__device__ __forceinline__ u64 pack_state(int flag, float v) {
    return ((u64)(unsigned)flag << 32) | (u64)__float_as_uint(v);
}

// Single-pass: per-chunk sum + decoupled lookback + |CDF| accumulation.
// state[b]: {flag,value}. flag 0 = invalid, 1 = aggregate, 2 = inclusive prefix.
__global__ __launch_bounds__(BLOCK) void k_emd_onepass(
    const float* __restrict__ x0, const float* __restrict__ x1,
    unsigned* __restrict__ ticket, u64* __restrict__ state,
    float* __restrict__ out, int n) {
    const int t = threadIdx.x;
    const int lane = t & 63;
    const int wave = t >> 6;

    __shared__ int s_bid;
    __shared__ float seg[NITER][BLOCK / 64];
    __shared__ float s_excl;
    __shared__ float wacc[BLOCK / 64];

    if (t == 0) s_bid = (int)atomicAdd(ticket, 1u);
    __syncthreads();
    const int bid = s_bid;
    const long base = (long)bid * CHUNK;

    // ---- single data read: per-thread 4-elem prefixes + wave scans ----
    float p[NITER][4];   // inclusive prefix within this thread's 4-elem group
    float tincl[NITER];  // wave-inclusive prefix of thread-group sums

#pragma unroll
    for (int k = 0; k < NITER; ++k) {
        long idx = base + (long)(k * BLOCK + t) * 4;
        float d0 = 0.f, d1 = 0.f, d2 = 0.f, d3 = 0.f;
        if (idx + 3 < n) {
            float4 a = *reinterpret_cast<const float4*>(x0 + idx);
            float4 b = *reinterpret_cast<const float4*>(x1 + idx);
            d0 = a.x - b.x; d1 = a.y - b.y; d2 = a.z - b.z; d3 = a.w - b.w;
        } else {
            if (idx + 0 < n) d0 = x0[idx + 0] - x1[idx + 0];
            if (idx + 1 < n) d1 = x0[idx + 1] - x1[idx + 1];
            if (idx + 2 < n) d2 = x0[idx + 2] - x1[idx + 2];
            if (idx + 3 < n) d3 = x0[idx + 3] - x1[idx + 3];
        }
        p[k][0] = d0;
        p[k][1] = p[k][0] + d1;
        p[k][2] = p[k][1] + d2;
        p[k][3] = p[k][2] + d3;
        float inc = wave_incl_scan(p[k][3], lane);
        tincl[k] = inc;
        if (lane == 63) seg[k][wave] = inc;
    }
    __syncthreads();

    // ---- block-level offsets per (iter, wave) + chunk aggregate ----
    float offk[NITER];
    float aggregate = 0.f;
    {
        float run = 0.f;
#pragma unroll
        for (int k = 0; k < NITER; ++k) {
            float woff = 0.f, ktot = 0.f;
#pragma unroll
            for (int w = 0; w < BLOCK / 64; ++w) {
                float v = seg[k][w];
                ktot += v;
                if (w < wave) woff += v;
            }
            offk[k] = run + woff;
            run += ktot;
        }
        aggregate = run;
    }

    // ---- publish aggregate, decoupled lookback (wave 0) ----
    if (t == 0) {
        __hip_atomic_store(&state[bid], pack_state(1, aggregate),
                           __ATOMIC_RELEASE, __HIP_MEMORY_SCOPE_AGENT);
    }
    if (wave == 0) {
        float excl = 0.f;
        int idx = bid - 1;
        while (idx >= 0) {
            int look = idx - lane;
            u64 st = (look >= 0)
                ? __hip_atomic_load(&state[look], __ATOMIC_ACQUIRE,
                                    __HIP_MEMORY_SCOPE_AGENT)
                : pack_state(2, 0.f);
            int flag = (int)(st >> 32);
            float val = __uint_as_float((unsigned)st);
            u64 b2 = __ballot(flag == 2);
            u64 b0 = __ballot(flag == 0);
            if (b2) {
                int pc = __ffsll(b2) - 1;  // closest block with inclusive prefix
                u64 mask = (pc == 0) ? 0ull : ((1ull << pc) - 1ull);
                if ((b0 & mask) == 0) {
                    float c = (lane <= pc) ? val : 0.f;
                    excl += wave_reduce_bcast(c);
                    break;
                }
            } else if (b0 == 0) {
                excl += wave_reduce_bcast(val);  // 64 aggregates, keep walking
                idx -= 64;
            }
            // else: spin, re-read window
        }
        if (lane == 0) {
            __hip_atomic_store(&state[bid], pack_state(2, excl + aggregate),
                               __ATOMIC_RELEASE, __HIP_MEMORY_SCOPE_AGENT);
            s_excl = excl;
        }
    }
    __syncthreads();
    const float excl = s_excl;

    // ---- accumulate |CDF| ----
    float acc = 0.f;
#pragma unroll
    for (int k = 0; k < NITER; ++k) {
        long idx = base + (long)(k * BLOCK + t) * 4;
        float boff = excl + offk[k] + (tincl[k] - p[k][3]);  // exclusive for thread
        if (idx + 0 < n) acc += fabsf(boff + p[k][0]);
        if (idx + 1 < n) acc += fabsf(boff + p[k][1]);
        if (idx + 2 < n) acc += fabsf(boff + p[k][2]);
        if (idx + 3 < n) acc += fabsf(boff + p[k][3]);
    }
    acc = wave_reduce(acc);
    if (lane == 0) wacc[wave] = acc;
    __syncthreads();
    if (t == 0) {
        float tot = 0.f;
#pragma unroll
        for (int w = 0; w < BLOCK / 64; ++w) tot += wacc[w];
        atomicAdd(out, tot);
    }
}

extern "C" void kernel_launch(void* const* d_in, const int* in_sizes, int n_in,
                              void* d_out, int out_size, void* d_ws, size_t ws_size,
                              hipStream_t stream) {
    const float* x = (const float*)d_in[0];
    const int total = in_sizes[0];
    const int n = total / 2;  // 8388608
    const float* x0 = x;
    const float* x1 = x + n;
    float* out = (float*)d_out;

    // ws layout: [0..3] ticket, [16 ..] state (8B per block)
    unsigned* ticket = (unsigned*)d_ws;
    u64* state = (u64*)((char*)d_ws + 16);

    const int B = (n + CHUNK - 1) / CHUNK;  // 2048

    hipMemsetAsync(d_ws, 0, 16 + (size_t)B * sizeof(u64), stream);
    hipMemsetAsync(out, 0, sizeof(float), stream);
    k_emd_onepass<<<B, BLOCK, 0, stream>>>(x0, x1, ticket, state, out, n);
}

// Round 6
// 122.119 us; speedup vs baseline: 2.0941x; 2.0941x over previous
//
#include <hip/hip_runtime.h>

#define BLOCK 256
#define CHUNK 4096                   // elements per block
#define NITER (CHUNK / (BLOCK * 4))  // 4 float4-pair iterations
#define NBLK 2048                    // 2^23 / 4096

__device__ __forceinline__ float wave_incl_scan(float v, int lane) {
#pragma unroll
    for (int off = 1; off < 64; off <<= 1) {
        float u = __shfl_up(v, off);
        if (lane >= off) v += u;
    }
    return v;
}

__device__ __forceinline__ float wave_reduce(float v) {
#pragma unroll
    for (int off = 32; off >= 1; off >>= 1) v += __shfl_down(v, off);
    return v;  // valid in lane 0
}

// k1: per-block (contiguous 4096-elem chunk) sum of d = x0 - x1. Streams HBM.
__global__ __launch_bounds__(BLOCK) void k_partial(const float* __restrict__ x0,
                                                   const float* __restrict__ x1,
                                                   float* __restrict__ partials,
                                                   int n) {
    const int t = threadIdx.x;
    const int lane = t & 63;
    const int wave = t >> 6;
    const long base = (long)blockIdx.x * CHUNK;
    float s = 0.f;
#pragma unroll
    for (int k = 0; k < NITER; ++k) {
        long idx = base + (long)(k * BLOCK + t) * 4;
        if (idx + 3 < n) {
            float4 a = *reinterpret_cast<const float4*>(x0 + idx);
            float4 b = *reinterpret_cast<const float4*>(x1 + idx);
            s += (a.x - b.x) + (a.y - b.y) + (a.z - b.z) + (a.w - b.w);
        } else {
#pragma unroll
            for (int j = 0; j < 4; ++j) {
                long i = idx + j;
                if (i < n) s += x0[i] - x1[i];
            }
        }
    }
    s = wave_reduce(s);
    __shared__ float ws[BLOCK / 64];
    if (lane == 0) ws[wave] = s;
    __syncthreads();
    if (t == 0) {
        float tot = 0.f;
#pragma unroll
        for (int w = 0; w < BLOCK / 64; ++w) tot += ws[w];
        partials[blockIdx.x] = tot;
        if (blockIdx.x == 0) *(float*)(partials + NBLK) = 0.f;  // unused slot
    }
}

// k2: predecessor-sum (8 KB from L2) + re-read chunk (L3-resident) +
//     local prefix + |CDF| accumulate + one atomicAdd.
__global__ __launch_bounds__(BLOCK) void k_emd(const float* __restrict__ x0,
                                               const float* __restrict__ x1,
                                               const float* __restrict__ partials,
                                               float* __restrict__ out, int n) {
    const int t = threadIdx.x;
    const int lane = t & 63;
    const int wave = t >> 6;
    const int bid = blockIdx.x;
    const long base = (long)bid * CHUNK;

    __shared__ float red[BLOCK / 64];
    __shared__ float wsum[BLOCK / 64];

    // zero out (first block only writes; all blocks atomically add later —
    // ensure deterministic init: every block adds to out, so init must
    // happen before any add. Do it via k1? Simpler: out is poisoned 0xAA,
    // so k1's thread 0 of block 0 can't init for k2 reliably across launch
    // boundary... instead use partials[NBLK] trick? No — memsetAsync in
    // launcher handles it (graph-capture-safe).

    // ---- exclusive block offset: sum partials[0..bid-1] ----
    float s = 0.f;
    for (int j = 0; j < NBLK / BLOCK; ++j) {
        int i = j * BLOCK + t;
        if (i < bid) s += partials[i];
    }
    s = wave_reduce(s);
    if (lane == 0) red[wave] = s;
    __syncthreads();
    float excl = 0.f;
#pragma unroll
    for (int w = 0; w < BLOCK / 64; ++w) excl += red[w];

    // ---- re-read chunk (L3-hot from k1), prefix, |CDF| ----
    float acc = 0.f;
    float run = excl;
#pragma unroll
    for (int k = 0; k < NITER; ++k) {
        long idx = base + (long)(k * BLOCK + t) * 4;
        float d0 = 0.f, d1 = 0.f, d2 = 0.f, d3 = 0.f;
        if (idx + 3 < n) {
            float4 a = *reinterpret_cast<const float4*>(x0 + idx);
            float4 b = *reinterpret_cast<const float4*>(x1 + idx);
            d0 = a.x - b.x; d1 = a.y - b.y; d2 = a.z - b.z; d3 = a.w - b.w;
        } else {
            if (idx + 0 < n) d0 = x0[idx + 0] - x1[idx + 0];
            if (idx + 1 < n) d1 = x0[idx + 1] - x1[idx + 1];
            if (idx + 2 < n) d2 = x0[idx + 2] - x1[idx + 2];
            if (idx + 3 < n) d3 = x0[idx + 3] - x1[idx + 3];
        }
        float p0 = d0, p1 = p0 + d1, p2 = p1 + d2, p3 = p2 + d3;
        float inc = wave_incl_scan(p3, lane);
        if (lane == 63) wsum[wave] = inc;
        __syncthreads();
        float wexcl = 0.f, ctot = 0.f;
#pragma unroll
        for (int w = 0; w < BLOCK / 64; ++w) {
            float v = wsum[w];
            ctot += v;
            if (w < wave) wexcl += v;
        }
        float boff = run + wexcl + (inc - p3);  // thread-exclusive prefix
        if (idx + 0 < n) acc += fabsf(boff + p0);
        if (idx + 1 < n) acc += fabsf(boff + p1);
        if (idx + 2 < n) acc += fabsf(boff + p2);
        if (idx + 3 < n) acc += fabsf(boff + p3);
        run += ctot;
        __syncthreads();  // wsum reused
    }
    acc = wave_reduce(acc);
    if (lane == 0) red[wave] = acc;
    __syncthreads();
    if (t == 0) {
        float tot = 0.f;
#pragma unroll
        for (int w = 0; w < BLOCK / 64; ++w) tot += red[w];
        atomicAdd(out, tot);
    }
}

extern "C" void kernel_launch(void* const* d_in, const int* in_sizes, int n_in,
                              void* d_out, int out_size, void* d_ws, size_t ws_size,
                              hipStream_t stream) {
    const float* x = (const float*)d_in[0];
    const int total = in_sizes[0];
    const int n = total / 2;  // 8388608
    const float* x0 = x;
    const float* x1 = x + n;
    float* out = (float*)d_out;
    float* partials = (float*)d_ws;

    hipMemsetAsync(out, 0, sizeof(float), stream);
    k_partial<<<NBLK, BLOCK, 0, stream>>>(x0, x1, partials, n);
    k_emd<<<NBLK, BLOCK, 0, stream>>>(x0, x1, partials, out, n);
}

// Round 8
// 121.848 us; speedup vs baseline: 2.0988x; 1.0022x over previous
//
#include <hip/hip_runtime.h>

#define BLOCK 256
#define CHUNK 4096                   // elements per block
#define NITER (CHUNK / (BLOCK * 4))  // 4 float4-pair iterations
#define NBLK 2048                    // 2^23 / 4096

__device__ __forceinline__ float wave_incl_scan(float v, int lane) {
#pragma unroll
    for (int off = 1; off < 64; off <<= 1) {
        float u = __shfl_up(v, off);
        if (lane >= off) v += u;
    }
    return v;
}

__device__ __forceinline__ float wave_reduce(float v) {
#pragma unroll
    for (int off = 32; off >= 1; off >>= 1) v += __shfl_down(v, off);
    return v;  // valid in lane 0
}

// k1: per-block chunk sum of d = x0 - x1 (streams input), also inits out.
__global__ __launch_bounds__(BLOCK) void k_partial(const float* __restrict__ x0,
                                                   const float* __restrict__ x1,
                                                   float* __restrict__ partials,
                                                   float* __restrict__ out, int n) {
    const int t = threadIdx.x;
    const int lane = t & 63;
    const int wave = t >> 6;
    const long base = (long)blockIdx.x * CHUNK;
    if (blockIdx.x == 0 && t == 0) *out = 0.f;  // ordered before k_emd's atomics
    float s = 0.f;
#pragma unroll
    for (int k = 0; k < NITER; ++k) {
        long idx = base + (long)(k * BLOCK + t) * 4;
        if (idx + 3 < n) {
            float4 a = *reinterpret_cast<const float4*>(x0 + idx);
            float4 b = *reinterpret_cast<const float4*>(x1 + idx);
            s += (a.x - b.x) + (a.y - b.y) + (a.z - b.z) + (a.w - b.w);
        } else {
#pragma unroll
            for (int j = 0; j < 4; ++j) {
                long i = idx + j;
                if (i < n) s += x0[i] - x1[i];
            }
        }
    }
    s = wave_reduce(s);
    __shared__ float ws[BLOCK / 64];
    if (lane == 0) ws[wave] = s;
    __syncthreads();
    if (t == 0) {
        float tot = 0.f;
#pragma unroll
        for (int w = 0; w < BLOCK / 64; ++w) tot += ws[w];
        partials[blockIdx.x] = tot;
    }
}

// k2: loads up front + predecessor-sum overlapped + 2 barriers total.
__global__ __launch_bounds__(BLOCK) void k_emd(const float* __restrict__ x0,
                                               const float* __restrict__ x1,
                                               const float* __restrict__ partials,
                                               float* __restrict__ out, int n) {
    const int t = threadIdx.x;
    const int lane = t & 63;
    const int wave = t >> 6;
    const int bid = blockIdx.x;
    const long base = (long)bid * CHUNK;

    __shared__ float red[BLOCK / 64];
    __shared__ float seg[NITER][BLOCK / 64];
    __shared__ float wacc[BLOCK / 64];

    // ---- 1) issue ALL data loads into registers (in flight immediately) ----
    float4 va[NITER], vb[NITER];
#pragma unroll
    for (int k = 0; k < NITER; ++k) {
        long idx = base + (long)(k * BLOCK + t) * 4;
        if (idx + 3 < n) {
            va[k] = *reinterpret_cast<const float4*>(x0 + idx);
            vb[k] = *reinterpret_cast<const float4*>(x1 + idx);
        } else {
            float4 a = {0.f, 0.f, 0.f, 0.f}, b = {0.f, 0.f, 0.f, 0.f};
            if (idx + 0 < n) { a.x = x0[idx + 0]; b.x = x1[idx + 0]; }
            if (idx + 1 < n) { a.y = x0[idx + 1]; b.y = x1[idx + 1]; }
            if (idx + 2 < n) { a.z = x0[idx + 2]; b.z = x1[idx + 2]; }
            va[k] = a; vb[k] = b;
        }
    }

    // ---- 2) predecessor sum (L2-resident 8 KB), overlaps load latency ----
    float s = 0.f;
    for (int j = 0; j * BLOCK < (int)gridDim.x; ++j) {
        int i = j * BLOCK + t;
        if (i < bid) s += partials[i];
    }
    s = wave_reduce(s);
    if (lane == 0) red[wave] = s;

    // ---- 3) thread-local prefixes + 4 independent wave scans ----
    float p[NITER][4], tincl[NITER];
#pragma unroll
    for (int k = 0; k < NITER; ++k) {
        float d0 = va[k].x - vb[k].x;
        float d1 = va[k].y - vb[k].y;
        float d2 = va[k].z - vb[k].z;
        float d3 = va[k].w - vb[k].w;
        p[k][0] = d0;
        p[k][1] = p[k][0] + d1;
        p[k][2] = p[k][1] + d2;
        p[k][3] = p[k][2] + d3;
        tincl[k] = wave_incl_scan(p[k][3], lane);
        if (lane == 63) seg[k][wave] = tincl[k];
    }
    __syncthreads();  // single barrier publishes red[] and seg[]

    // ---- 4) block offsets + |CDF| accumulate ----
    float excl = 0.f;
#pragma unroll
    for (int w = 0; w < BLOCK / 64; ++w) excl += red[w];

    float acc = 0.f;
    float run = excl;
#pragma unroll
    for (int k = 0; k < NITER; ++k) {
        float woff = 0.f, ktot = 0.f;
#pragma unroll
        for (int w = 0; w < BLOCK / 64; ++w) {
            float v = seg[k][w];
            ktot += v;
            if (w < wave) woff += v;
        }
        float boff = run + woff + (tincl[k] - p[k][3]);  // thread-exclusive
        long idx = base + (long)(k * BLOCK + t) * 4;
        if (idx + 0 < n) acc += fabsf(boff + p[k][0]);
        if (idx + 1 < n) acc += fabsf(boff + p[k][1]);
        if (idx + 2 < n) acc += fabsf(boff + p[k][2]);
        if (idx + 3 < n) acc += fabsf(boff + p[k][3]);
        run += ktot;
    }

    // ---- 5) block reduce + one atomic ----
    acc = wave_reduce(acc);
    if (lane == 0) wacc[wave] = acc;
    __syncthreads();
    if (t == 0) {
        float tot = 0.f;
#pragma unroll
        for (int w = 0; w < BLOCK / 64; ++w) tot += wacc[w];
        atomicAdd(out, tot);
    }
}

extern "C" void kernel_launch(void* const* d_in, const int* in_sizes, int n_in,
                              void* d_out, int out_size, void* d_ws, size_t ws_size,
                              hipStream_t stream) {
    const float* x = (const float*)d_in[0];
    const int total = in_sizes[0];
    const int n = total / 2;  // 8388608
    const float* x0 = x;
    const float* x1 = x + n;
    float* out = (float*)d_out;
    float* partials = (float*)d_ws;

    const int B = (n + CHUNK - 1) / CHUNK;  // 2048

    k_partial<<<B, BLOCK, 0, stream>>>(x0, x1, partials, out, n);
    k_emd<<<B, BLOCK, 0, stream>>>(x0, x1, partials, out, n);
}